// Round 5
// baseline (97.089 us; speedup 1.0000x reference)
//
#include <hip/hip_runtime.h>
#include <hip/hip_cooperative_groups.h>

namespace cg = cooperative_groups;

#define D  128   // EMB
#define KN 128   // K_N
#define NB 16    // batch rows per block
#define LOG2E 1.44269504088896340736f

__device__ __forceinline__ float negexp(float v) {              // e^{-v}
    return __builtin_amdgcn_exp2f(v * -LOG2E);
}
__device__ __forceinline__ float sigf(float x) {                // sigmoid
    return __builtin_amdgcn_rcpf(1.0f + negexp(x));
}

// ---- LDS union: phase A (prep dots) vs phase B (main loop) ----------------
struct SharedA {
    float W1T[D][132];      // |W1[:, :128]|^T, pad 132 (16B-aligned float4 rows)
    float W2T[D][132];
    float SV[NB][D];
    float EV[NB][D];
};                           // 151552 B
struct SharedB {
    float4 TAB[D * 64];     // [e][l] = {E1(e,2l),E1(e,2l+1),E2(e,2l),E2(e,2l+1)}
    float4 EAp[NB][D / 2];  // [b][j] = {Ea1(2j),Ea2(2j),Ea1(2j+1),Ea2(2j+1)}
    float2 PZp[NB][D / 2];  // [b][j] = {pz(2j),pz(2j+1)}
};                           // 155648 B  (EAp/PZp live across grid.sync; TAB
                             //  overwrites only the dead W1T/W2T region)
union SharedU { SharedA a; SharedB b; };

// 2 elements (k=2l,2l+1) of one (b,e):  x'=1+Ea1*E1, y'=1+Ea2*E2,
// acc += (y'-x')*pz / (x'*y')   [== sigma(a)-sigma(b), scaled]
#define CORE(EA1, EA2, T, PZ, A0, A1) do {                                   \
    float x0_ = fmaf((EA1), (T).x, 1.0f);                                    \
    float x1_ = fmaf((EA1), (T).y, 1.0f);                                    \
    float y0_ = fmaf((EA2), (T).z, 1.0f);                                    \
    float y1_ = fmaf((EA2), (T).w, 1.0f);                                    \
    (A0) = fmaf((y0_ - x0_) * (PZ), __builtin_amdgcn_rcpf(x0_ * y0_), (A0)); \
    (A1) = fmaf((y1_ - x1_) * (PZ), __builtin_amdgcn_rcpf(x1_ * y1_), (A1)); \
} while (0)

__global__ __launch_bounds__(512, 1) void fused_kernel(
    const int* __restrict__ stu_id, const int* __restrict__ exer_id,
    const float* __restrict__ kq,
    const float* __restrict__ stu_q, const float* __restrict__ exer_k,
    const float* __restrict__ stu_v, const float* __restrict__ exer_v,
    const float* __restrict__ kn,
    const float* __restrict__ W1, const float* __restrict__ b1,
    const float* __restrict__ W2, const float* __restrict__ b2,
    const float* __restrict__ W3, const float* __restrict__ b3,
    float* __restrict__ TABGf, float* __restrict__ out, int B)
{
    __shared__ SharedU sh;
    __shared__ int sids[NB], eids[NB];

    const int tid   = threadIdx.x;
    const int b0blk = blockIdx.x * NB;

    // ---------------- Phase A: stage ----------------
    if (tid < NB) {
        int b = b0blk + tid;
        sids[tid] = stu_id[b < B ? b : 0];
        eids[tid] = exer_id[b < B ? b : 0];
    }
    for (int i = tid; i < D * D; i += 512) {     // coalesced global read
        int e = i >> 7, d = i & (D - 1);
        sh.a.W1T[d][e] = fabsf(W1[e * (2 * D) + d]);
        sh.a.W2T[d][e] = fabsf(W2[e * (2 * D) + d]);
    }
    __syncthreads();
    for (int i = tid; i < NB * D; i += 512) {
        int bi = i >> 7, d = i & (D - 1);
        sh.a.SV[bi][d] = stu_v[(size_t)sids[bi] * D + d];
        sh.a.EV[bi][d] = exer_v[(size_t)eids[bi] * D + d];
    }
    __syncthreads();

    // ---------------- Phase A: compute ----------------
    const int eg  = tid & 31;            // 4-e group
    const int bh  = (tid >> 5) & 7;      // b-pair slot
    const int bi0 = 2 * bh, bi1 = 2 * bh + 1;
    float4 as0 = {0, 0, 0, 0}, as1 = as0, ae0 = as0, ae1 = as0;

    if (tid < 256) {
        // prep role: S1/E2 dots for 2 b's x 4 e's
        #pragma unroll 4
        for (int d = 0; d < D; ++d) {
            float4 w1 = *(const float4*)&sh.a.W1T[d][eg * 4];
            float4 w2 = *(const float4*)&sh.a.W2T[d][eg * 4];
            float sv0 = sh.a.SV[bi0][d], sv1 = sh.a.SV[bi1][d];   // broadcast
            float ev0 = sh.a.EV[bi0][d], ev1 = sh.a.EV[bi1][d];
            as0.x = fmaf(sv0, w1.x, as0.x); as0.y = fmaf(sv0, w1.y, as0.y);
            as0.z = fmaf(sv0, w1.z, as0.z); as0.w = fmaf(sv0, w1.w, as0.w);
            as1.x = fmaf(sv1, w1.x, as1.x); as1.y = fmaf(sv1, w1.y, as1.y);
            as1.z = fmaf(sv1, w1.z, as1.z); as1.w = fmaf(sv1, w1.w, as1.w);
            ae0.x = fmaf(ev0, w2.x, ae0.x); ae0.y = fmaf(ev0, w2.y, ae0.y);
            ae0.z = fmaf(ev0, w2.z, ae0.z); ae0.w = fmaf(ev0, w2.w, ae0.w);
            ae1.x = fmaf(ev1, w2.x, ae1.x); ae1.y = fmaf(ev1, w2.y, ae1.y);
            ae1.z = fmaf(ev1, w2.z, ae1.z); ae1.w = fmaf(ev1, w2.w, ae1.w);
        }
    } else if (blockIdx.x < 64) {
        // tables role: one (e,k) entry per thread; 64 blocks cover 128x128
        const int idx = blockIdx.x * 256 + (tid - 256);
        const int e = idx >> 7, k = idx & (KN - 1);
        const float4* knr = (const float4*)(kn + (size_t)k * D);
        const float4* w1r = (const float4*)(W1 + (size_t)e * (2 * D) + D);
        const float4* w2r = (const float4*)(W2 + (size_t)e * (2 * D) + D);
        float a1 = 0.f, a2 = 0.f;
        #pragma unroll 8
        for (int q = 0; q < D / 4; ++q) {
            float4 kv = knr[q], u = w1r[q], v = w2r[q];
            a1 = fmaf(kv.x, fabsf(u.x), a1); a1 = fmaf(kv.y, fabsf(u.y), a1);
            a1 = fmaf(kv.z, fabsf(u.z), a1); a1 = fmaf(kv.w, fabsf(u.w), a1);
            a2 = fmaf(kv.x, fabsf(v.x), a2); a2 = fmaf(kv.y, fabsf(v.y), a2);
            a2 = fmaf(kv.z, fabsf(v.z), a2); a2 = fmaf(kv.w, fabsf(v.w), a2);
        }
        const int base = e * 256 + (k >> 1) * 4 + (k & 1);   // TAB float4 layout
        TABGf[base]     = negexp(a1 + b1[e]);
        TABGf[base + 2] = negexp(a2 + b2[e]);
    }
    __syncthreads();   // all W1T/W2T/SV/EV reads complete -> EAp/PZp may alias

    if (tid < 256) {
        float4 w3 = *(const float4*)(W3 + eg * 4);
        float4 w3a = make_float4(fabsf(w3.x), fabsf(w3.y), fabsf(w3.z), fabsf(w3.w));
        if (b0blk + bi0 < B) {
            int b = b0blk + bi0;
            float4 sq = *(const float4*)(stu_q + (size_t)sids[bi0] * D + eg * 4);
            float4 ek = *(const float4*)(exer_k + (size_t)eids[bi0] * D + eg * 4);
            sh.b.EAp[bi0][eg*2]   = make_float4(negexp(as0.x), negexp(ae0.x), negexp(as0.y), negexp(ae0.y));
            sh.b.EAp[bi0][eg*2+1] = make_float4(negexp(as0.z), negexp(ae0.z), negexp(as0.w), negexp(ae0.w));
            sh.b.PZp[bi0][eg*2]   = make_float2(sigf(sq.x*ek.x)*w3a.x, sigf(sq.y*ek.y)*w3a.y);
            sh.b.PZp[bi0][eg*2+1] = make_float2(sigf(sq.z*ek.z)*w3a.z, sigf(sq.w*ek.w)*w3a.w);
            (void)b;
        }
        if (b0blk + bi1 < B) {
            float4 sq = *(const float4*)(stu_q + (size_t)sids[bi1] * D + eg * 4);
            float4 ek = *(const float4*)(exer_k + (size_t)eids[bi1] * D + eg * 4);
            sh.b.EAp[bi1][eg*2]   = make_float4(negexp(as1.x), negexp(ae1.x), negexp(as1.y), negexp(ae1.y));
            sh.b.EAp[bi1][eg*2+1] = make_float4(negexp(as1.z), negexp(ae1.z), negexp(as1.w), negexp(ae1.w));
            sh.b.PZp[bi1][eg*2]   = make_float2(sigf(sq.x*ek.x)*w3a.x, sigf(sq.y*ek.y)*w3a.y);
            sh.b.PZp[bi1][eg*2+1] = make_float2(sigf(sq.z*ek.z)*w3a.z, sigf(sq.w*ek.w)*w3a.w);
        }
    }

    __threadfence();          // TABG stores device-visible (belt+braces)
    cg::this_grid().sync();   // tables + all blocks' EAp/PZp ready

    // ---------------- Phase B ----------------
    const float4* TABG4 = (const float4*)TABGf;
    #pragma unroll
    for (int it = 0; it < 16; ++it) {       // 128KB TAB stage (overwrites W region)
        int j = tid + it * 512;
        sh.b.TAB[j] = TABG4[j];
    }
    __syncthreads();

    const int wid = tid >> 6, lane = tid & 63;
    const float b3v = b3[0];
    const int rA = 2 * wid, rB = 2 * wid + 1;       // this wave's 2 b-rows
    const int bA = b0blk + rA, bB = b0blk + rB;

    float acc0a = 0.f, acc1a = 0.f, acc0b = 0.f, acc1b = 0.f;
    #pragma unroll 2
    for (int j = 0; j < D / 2; ++j) {               // 2 e per iter, 8 elem/lane
        float4 t0 = sh.b.TAB[(2 * j) * 64 + lane];
        float4 t1 = sh.b.TAB[(2 * j + 1) * 64 + lane];
        float4 eA = sh.b.EAp[rA][j]; float2 zA = sh.b.PZp[rA][j];   // broadcasts
        float4 eB = sh.b.EAp[rB][j]; float2 zB = sh.b.PZp[rB][j];
        CORE(eA.x, eA.y, t0, zA.x, acc0a, acc1a);
        CORE(eA.z, eA.w, t1, zA.y, acc0a, acc1a);
        CORE(eB.x, eB.y, t0, zB.x, acc0b, acc1b);
        CORE(eB.z, eB.w, t1, zB.y, acc0b, acc1b);
    }

    float o0a = sigf(acc0a + b3v), o1a = sigf(acc1a + b3v);
    float o0b = sigf(acc0b + b3v), o1b = sigf(acc1b + b3v);
    float na = 0.f, da = 0.f, nb = 0.f, db = 0.f;
    if (bA < B) {
        float2 kqa = *(const float2*)(kq + (size_t)bA * D + 2 * lane);
        na = fmaf(o0a, kqa.x, o1a * kqa.y); da = kqa.x + kqa.y;
    }
    if (bB < B) {
        float2 kqb = *(const float2*)(kq + (size_t)bB * D + 2 * lane);
        nb = fmaf(o0b, kqb.x, o1b * kqb.y); db = kqb.x + kqb.y;
    }
    #pragma unroll
    for (int off = 32; off > 0; off >>= 1) {
        na += __shfl_xor(na, off); da += __shfl_xor(da, off);
        nb += __shfl_xor(nb, off); db += __shfl_xor(db, off);
    }
    if (lane == 0) {
        if (bA < B) out[bA] = na / da;
        if (bB < B) out[bB] = nb / db;
    }
}

// ---------------------------------------------------------------------------
extern "C" void kernel_launch(void* const* d_in, const int* in_sizes, int n_in,
                              void* d_out, int out_size, void* d_ws, size_t ws_size,
                              hipStream_t stream)
{
    const int*   stu_id      = (const int*)  d_in[0];
    const int*   exer_id     = (const int*)  d_in[1];
    const float* kq          = (const float*)d_in[2];
    const float* student_q   = (const float*)d_in[3];
    const float* exercise_k  = (const float*)d_in[4];
    const float* student_v   = (const float*)d_in[5];
    const float* exercise_v  = (const float*)d_in[6];
    const float* knowledge_v = (const float*)d_in[7];
    const float* W1 = (const float*)d_in[8];
    const float* b1 = (const float*)d_in[9];
    const float* W2 = (const float*)d_in[10];
    const float* b2 = (const float*)d_in[11];
    const float* W3 = (const float*)d_in[12];
    const float* b3 = (const float*)d_in[13];
    float* out = (float*)d_out;
    int B = in_sizes[0];

    float* TABGf = (float*)d_ws;   // 128KB interleaved exp-tables

    int nblk = (B + NB - 1) / NB;
    if (nblk < 64)  nblk = 64;     // tables role needs blocks 0..63
    if (nblk > 256) nblk = 256;    // co-residency bound (B<=4096 in harness)

    void* args[] = {
        (void*)&stu_id, (void*)&exer_id, (void*)&kq,
        (void*)&student_q, (void*)&exercise_k,
        (void*)&student_v, (void*)&exercise_v,
        (void*)&knowledge_v,
        (void*)&W1, (void*)&b1, (void*)&W2, (void*)&b2,
        (void*)&W3, (void*)&b3,
        (void*)&TABGf, (void*)&out, (void*)&B,
    };
    hipLaunchCooperativeKernel((void*)fused_kernel, dim3(nblk), dim3(512),
                               args, 0, stream);
}

// Round 6
// 32.407 us; speedup vs baseline: 2.9959x; 2.9959x over previous
//
#include <hip/hip_runtime.h>

#define D  128   // EMB
#define KN 128   // K_N
#define NB 16    // batch rows per block
#define LOG2E 1.44269504088896340736f

typedef float f32x4  __attribute__((ext_vector_type(4)));
typedef float f32x16 __attribute__((ext_vector_type(16)));
typedef short s16x8  __attribute__((ext_vector_type(8)));   // 8 bf16 (4 VGPR)

__device__ __forceinline__ float negexp(float v) {              // e^{-v}
    return __builtin_amdgcn_exp2f(v * -LOG2E);
}
__device__ __forceinline__ float sigf(float x) {                // sigmoid
    return __builtin_amdgcn_rcpf(1.0f + negexp(x));
}
__device__ __forceinline__ unsigned short f2bf(float f) {       // fp32->bf16 RNE
    unsigned u = __float_as_uint(f);
    return (unsigned short)((u + 0x7fffu + ((u >> 16) & 1u)) >> 16);
}
__device__ __forceinline__ s16x8 pack8(float4 a, float4 b) {
    s16x8 r;
    r[0]=(short)f2bf(a.x); r[1]=(short)f2bf(a.y); r[2]=(short)f2bf(a.z); r[3]=(short)f2bf(a.w);
    r[4]=(short)f2bf(b.x); r[5]=(short)f2bf(b.y); r[6]=(short)f2bf(b.z); r[7]=(short)f2bf(b.w);
    return r;
}
__device__ __forceinline__ s16x8 pack8abs(float4 a, float4 b) {
    s16x8 r;
    r[0]=(short)f2bf(fabsf(a.x)); r[1]=(short)f2bf(fabsf(a.y)); r[2]=(short)f2bf(fabsf(a.z)); r[3]=(short)f2bf(fabsf(a.w));
    r[4]=(short)f2bf(fabsf(b.x)); r[5]=(short)f2bf(fabsf(b.y)); r[6]=(short)f2bf(fabsf(b.z)); r[7]=(short)f2bf(fabsf(b.w));
    return r;
}

// phase-B core: 2 elements (k=2l,2l+1) of one (b,e)
#define CORE(EA1, EA2, T, PZ, A0, A1) do {                                   \
    float x0_ = fmaf((EA1), (T).x, 1.0f);                                    \
    float x1_ = fmaf((EA1), (T).y, 1.0f);                                    \
    float y0_ = fmaf((EA2), (T).z, 1.0f);                                    \
    float y1_ = fmaf((EA2), (T).w, 1.0f);                                    \
    (A0) = fmaf((y0_ - x0_) * (PZ), __builtin_amdgcn_rcpf(x0_ * y0_), (A0)); \
    (A1) = fmaf((y1_ - x1_) * (PZ), __builtin_amdgcn_rcpf(x1_ * y1_), (A1)); \
} while (0)

// tables GEMM: one 32x32 tile (8 K-steps) accumulating into ACC
#define TTILE(T, ACC) {                                                       \
    const int idx_ = (wid << 2) + (T);                                        \
    const char* Wsb_ = (idx_ < 16) ? W1s_base : W2s_base;                     \
    const int et_ = (idx_ >> 2) & 3, kt_ = idx_ & 3;                          \
    const int er_ = et_ * 32 + l31, kr_ = kt_ * 32 + l31;                     \
    const int eswz_ = (er_ & 7) << 4, kswz_ = (kr_ & 7) << 4;                 \
    _Pragma("unroll")                                                         \
    for (int q = 0; q < 8; ++q) {                                             \
        int dby = q * 32 + g32 * 16;                                          \
        s16x8 a_ = *(const s16x8*)(Wsb_ + er_ * 256 + (dby ^ eswz_));         \
        s16x8 b_ = *(const s16x8*)(KNs_base + kr_ * 256 + (dby ^ kswz_));     \
        ACC = __builtin_amdgcn_mfma_f32_32x32x16_bf16(a_, b_, ACC, 0, 0, 0);  \
    } }

// tables write: exp(-(acc+bias)) into interleaved TAB layout
//   TABf[e*256 + (k>>1)*4 + (k&1) + (0|2)]
#define TWRITE(T, ACC) {                                                      \
    const int idx_ = (wid << 2) + (T);                                        \
    const int et_ = (idx_ >> 2) & 3, kt_ = idx_ & 3;                          \
    const int slot_ = (idx_ < 16) ? 0 : 2;                                    \
    const float* bias_ = (idx_ < 16) ? b1 : b2;                               \
    const int k_ = kt_ * 32 + l31;                                            \
    const int kof_ = ((k_ >> 1) << 2) + (k_ & 1) + slot_;                     \
    _Pragma("unroll")                                                         \
    for (int r = 0; r < 16; ++r) {                                            \
        int e_ = et_ * 32 + (r & 3) + ((r >> 2) << 3) + (g32 << 2);           \
        TABf[e_ * 256 + kof_] = negexp(ACC[r] + bias_[e_]);                   \
    } }

__global__ __launch_bounds__(512, 1) void fused_kernel(
    const int* __restrict__ stu_id, const int* __restrict__ exer_id,
    const float* __restrict__ kq,
    const float* __restrict__ stu_q, const float* __restrict__ exer_k,
    const float* __restrict__ stu_v, const float* __restrict__ exer_v,
    const float* __restrict__ kn,
    const float* __restrict__ W1, const float* __restrict__ b1,
    const float* __restrict__ W2, const float* __restrict__ b2,
    const float* __restrict__ W3, const float* __restrict__ b3,
    float* __restrict__ out, int B)
{
    // LDS map (155648 B):
    //   [0,131072)       phase A: KNs(32K)|W1s(32K)|W2s(32K) bf16, XOR-swizzled
    //                    phase B: TAB float4[e][l] (written after sync2)
    //   [131072,147456)  EAf: Ea1/Ea2 interleaved, float ofs b*256 + 2e + {0,1}
    //   [147456,155648)  PZf: pz, float ofs b*128 + e
    __shared__ float4 smem4[9728];
    __shared__ int sids[NB], eids[NB];

    float* TABf = (float*)smem4;
    float* EAf  = TABf + 32768;
    float* PZf  = EAf + 4096;
    char* KNs_base = (char*)smem4;
    char* W1s_base = KNs_base + 32768;
    char* W2s_base = KNs_base + 65536;

    const int tid  = threadIdx.x;
    const int b0   = blockIdx.x * NB;
    const int lane = tid & 63, wid = tid >> 6;
    const int l31 = lane & 31, g32 = lane >> 5;
    const int l15 = lane & 15, g16 = lane >> 4;

    if (tid < NB) {
        int b = b0 + tid;
        sids[tid] = stu_id[b < B ? b : 0];
        eids[tid] = exer_id[b < B ? b : 0];
    }
    // ---- stage kn, |W1b|, |W2b| as bf16, row 256B, chunk-XOR-swizzled ----
    for (int i = tid; i < 128 * 16; i += 512) {
        int row = i >> 4, c = i & 15;
        int byt = row * 256 + (((c << 4)) ^ ((row & 7) << 4));
        const float4* sk = (const float4*)(kn + (size_t)row * D + c * 8);
        *(s16x8*)(KNs_base + byt) = pack8(sk[0], sk[1]);
        const float4* s1 = (const float4*)(W1 + (size_t)row * (2 * D) + D + c * 8);
        *(s16x8*)(W1s_base + byt) = pack8abs(s1[0], s1[1]);
        const float4* s2 = (const float4*)(W2 + (size_t)row * (2 * D) + D + c * 8);
        *(s16x8*)(W2s_base + byt) = pack8abs(s2[0], s2[1]);
    }
    __syncthreads();

    // ---- tables GEMM: 32 tiles of 32x32 over (e,k), 4/wave, accum in regs ----
    f32x16 t0acc = {0}, t1acc = {0}, t2acc = {0}, t3acc = {0};
    TTILE(0, t0acc) TTILE(1, t1acc) TTILE(2, t2acc) TTILE(3, t3acc)

    // ---- prep GEMM: C[16b x 16e] per wave (e-tile = wid), A/B from global ----
    const int sid_l = sids[l15], eid_l = eids[l15];
    const int erow  = wid * 16 + l15;
    f32x4 accS = {0, 0, 0, 0}, accE = {0, 0, 0, 0};
    #pragma unroll
    for (int q = 0; q < 4; ++q) {
        int d = q * 32 + g16 * 8;
        const float4* pa = (const float4*)(stu_v + (size_t)sid_l * D + d);
        const float4* pb = (const float4*)(W1 + (size_t)erow * (2 * D) + d);
        accS = __builtin_amdgcn_mfma_f32_16x16x32_bf16(
            pack8(pa[0], pa[1]), pack8abs(pb[0], pb[1]), accS, 0, 0, 0);
        const float4* pe = (const float4*)(exer_v + (size_t)eid_l * D + d);
        const float4* pc = (const float4*)(W2 + (size_t)erow * (2 * D) + d);
        accE = __builtin_amdgcn_mfma_f32_16x16x32_bf16(
            pack8(pe[0], pe[1]), pack8abs(pc[0], pc[1]), accE, 0, 0, 0);
    }
    // EA writes (region disjoint from staging -> no sync needed yet)
    #pragma unroll
    for (int r = 0; r < 4; ++r) {
        int b = g16 * 4 + r;
        int eo = b * 256 + 2 * erow;
        EAf[eo]     = negexp(accS[r]);
        EAf[eo + 1] = negexp(accE[r]);
    }
    // ---- PZ: disc * |w3|, thread = (b = tid>>5, 4 e's) ----
    {
        int b = tid >> 5, e4 = (tid & 31) << 2;
        float4 sq = *(const float4*)(stu_q + (size_t)sids[b] * D + e4);
        float4 ek = *(const float4*)(exer_k + (size_t)eids[b] * D + e4);
        float4 w3 = *(const float4*)(W3 + e4);
        float4 z;
        z.x = sigf(sq.x * ek.x) * fabsf(w3.x);
        z.y = sigf(sq.y * ek.y) * fabsf(w3.y);
        z.z = sigf(sq.z * ek.z) * fabsf(w3.z);
        z.w = sigf(sq.w * ek.w) * fabsf(w3.w);
        *(float4*)(PZf + b * D + e4) = z;
    }
    __syncthreads();   // all staged-LDS reads done -> TAB may overwrite

    TWRITE(0, t0acc) TWRITE(1, t1acc) TWRITE(2, t2acc) TWRITE(3, t3acc)
    __syncthreads();   // TAB/EA/PZ ready

    // ---------------- Phase B ----------------
    const float4* TAB4 = (const float4*)TABf;
    const float4* EA4  = (const float4*)EAf;
    const float2* PZ2  = (const float2*)PZf;
    const float b3v = b3[0];
    const int rA = 2 * wid, rB = 2 * wid + 1;
    const int bA = b0 + rA, bB = b0 + rB;

    float acc0a = 0.f, acc1a = 0.f, acc0b = 0.f, acc1b = 0.f;
    #pragma unroll 2
    for (int j = 0; j < D / 2; ++j) {               // 2 e x 2 k x 2 b per iter
        float4 t0 = TAB4[(2 * j) * 64 + lane];
        float4 t1 = TAB4[(2 * j + 1) * 64 + lane];
        float4 eA = EA4[rA * 64 + j]; float2 zA = PZ2[rA * 64 + j];
        float4 eB = EA4[rB * 64 + j]; float2 zB = PZ2[rB * 64 + j];
        CORE(eA.x, eA.y, t0, zA.x, acc0a, acc1a);
        CORE(eA.z, eA.w, t1, zA.y, acc0a, acc1a);
        CORE(eB.x, eB.y, t0, zB.x, acc0b, acc1b);
        CORE(eB.z, eB.w, t1, zB.y, acc0b, acc1b);
    }

    float o0a = sigf(acc0a + b3v), o1a = sigf(acc1a + b3v);
    float o0b = sigf(acc0b + b3v), o1b = sigf(acc1b + b3v);
    float na = 0.f, da = 0.f, nb = 0.f, db = 0.f;
    if (bA < B) {
        float2 kqa = *(const float2*)(kq + (size_t)bA * D + 2 * lane);
        na = fmaf(o0a, kqa.x, o1a * kqa.y); da = kqa.x + kqa.y;
    }
    if (bB < B) {
        float2 kqb = *(const float2*)(kq + (size_t)bB * D + 2 * lane);
        nb = fmaf(o0b, kqb.x, o1b * kqb.y); db = kqb.x + kqb.y;
    }
    #pragma unroll
    for (int off = 32; off > 0; off >>= 1) {
        na += __shfl_xor(na, off); da += __shfl_xor(da, off);
        nb += __shfl_xor(nb, off); db += __shfl_xor(db, off);
    }
    if (lane == 0) {
        if (bA < B) out[bA] = na / da;
        if (bB < B) out[bB] = nb / db;
    }
}

// ---------------------------------------------------------------------------
extern "C" void kernel_launch(void* const* d_in, const int* in_sizes, int n_in,
                              void* d_out, int out_size, void* d_ws, size_t ws_size,
                              hipStream_t stream)
{
    const int*   stu_id      = (const int*)  d_in[0];
    const int*   exer_id     = (const int*)  d_in[1];
    const float* kq          = (const float*)d_in[2];
    const float* student_q   = (const float*)d_in[3];
    const float* exercise_k  = (const float*)d_in[4];
    const float* student_v   = (const float*)d_in[5];
    const float* exercise_v  = (const float*)d_in[6];
    const float* knowledge_v = (const float*)d_in[7];
    const float* W1 = (const float*)d_in[8];
    const float* b1 = (const float*)d_in[9];
    const float* W2 = (const float*)d_in[10];
    const float* b2 = (const float*)d_in[11];
    const float* W3 = (const float*)d_in[12];
    const float* b3 = (const float*)d_in[13];
    float* out = (float*)d_out;
    const int B = in_sizes[0];

    int nblk = (B + NB - 1) / NB;
    fused_kernel<<<nblk, 512, 0, stream>>>(
        stu_id, exer_id, kq, student_q, exercise_k, student_v, exercise_v,
        knowledge_v, W1, b1, W2, b2, W3, b3, out, B);
}

// Round 7
// 31.431 us; speedup vs baseline: 3.0889x; 1.0311x over previous
//
#include <hip/hip_runtime.h>

#define D  128   // EMB
#define KN 128   // K_N
#define NB 16    // batch rows per block
#define LOG2E 1.44269504088896340736f

typedef float f32x4  __attribute__((ext_vector_type(4)));
typedef float f32x16 __attribute__((ext_vector_type(16)));
typedef short s16x8  __attribute__((ext_vector_type(8)));   // 8 bf16 (4 VGPR)

__device__ __forceinline__ float negexp(float v) {              // e^{-v}
    return __builtin_amdgcn_exp2f(v * -LOG2E);
}
__device__ __forceinline__ float sigf(float x) {                // sigmoid
    return __builtin_amdgcn_rcpf(1.0f + negexp(x));
}
__device__ __forceinline__ unsigned short f2bf(float f) {       // fp32->bf16 RNE
    unsigned u = __float_as_uint(f);
    return (unsigned short)((u + 0x7fffu + ((u >> 16) & 1u)) >> 16);
}
__device__ __forceinline__ s16x8 pack8(float4 a, float4 b) {
    s16x8 r;
    r[0]=(short)f2bf(a.x); r[1]=(short)f2bf(a.y); r[2]=(short)f2bf(a.z); r[3]=(short)f2bf(a.w);
    r[4]=(short)f2bf(b.x); r[5]=(short)f2bf(b.y); r[6]=(short)f2bf(b.z); r[7]=(short)f2bf(b.w);
    return r;
}
__device__ __forceinline__ s16x8 pack8abs(float4 a, float4 b) {
    s16x8 r;
    r[0]=(short)f2bf(fabsf(a.x)); r[1]=(short)f2bf(fabsf(a.y)); r[2]=(short)f2bf(fabsf(a.z)); r[3]=(short)f2bf(fabsf(a.w));
    r[4]=(short)f2bf(fabsf(b.x)); r[5]=(short)f2bf(fabsf(b.y)); r[6]=(short)f2bf(fabsf(b.z)); r[7]=(short)f2bf(fabsf(b.w));
    return r;
}

// phase-B core: 2 elements (k=2l,2l+1) of one (b,e)
#define CORE(EA1, EA2, T, PZ, A0, A1) do {                                   \
    float x0_ = fmaf((EA1), (T).x, 1.0f);                                    \
    float x1_ = fmaf((EA1), (T).y, 1.0f);                                    \
    float y0_ = fmaf((EA2), (T).z, 1.0f);                                    \
    float y1_ = fmaf((EA2), (T).w, 1.0f);                                    \
    (A0) = fmaf((y0_ - x0_) * (PZ), __builtin_amdgcn_rcpf(x0_ * y0_), (A0)); \
    (A1) = fmaf((y1_ - x1_) * (PZ), __builtin_amdgcn_rcpf(x1_ * y1_), (A1)); \
} while (0)

// tables write: exp(-(acc+bias)) into interleaved TAB layout
//   TABf[e*256 + (k>>1)*4 + (k&1) + (0|2)]
#define TWRITE(T, ACC) {                                                      \
    const int idx_ = (wid << 2) + (T);                                        \
    const int et_ = (idx_ >> 2) & 3, kt_ = idx_ & 3;                          \
    const int slot_ = (idx_ < 16) ? 0 : 2;                                    \
    const float* bias_ = (idx_ < 16) ? b1 : b2;                               \
    const int k_ = kt_ * 32 + l31;                                            \
    const int kof_ = ((k_ >> 1) << 2) + (k_ & 1) + slot_;                     \
    _Pragma("unroll")                                                         \
    for (int r = 0; r < 16; ++r) {                                            \
        int e_ = et_ * 32 + (r & 3) + ((r >> 2) << 3) + (g32 << 2);           \
        TABf[e_ * 256 + kof_] = negexp(ACC[r] + bias_[e_]);                   \
    } }

__global__ __launch_bounds__(512, 1) void fused_kernel(
    const int* __restrict__ stu_id, const int* __restrict__ exer_id,
    const float* __restrict__ kq,
    const float* __restrict__ stu_q, const float* __restrict__ exer_k,
    const float* __restrict__ stu_v, const float* __restrict__ exer_v,
    const float* __restrict__ kn,
    const float* __restrict__ W1, const float* __restrict__ b1,
    const float* __restrict__ W2, const float* __restrict__ b2,
    const float* __restrict__ W3, const float* __restrict__ b3,
    float* __restrict__ out, int B)
{
    // LDS map (155648 B):
    //   [0,131072)       phase A: KNs(32K)|W1s(32K)|W2s(32K) bf16, XOR-swizzled
    //                    phase B: TAB float4[e][l]; then RED float2[8][16][64]
    //   [131072,147456)  EAf: Ea1/Ea2 interleaved, float ofs b*256 + 2e + {0,1}
    //   [147456,155648)  PZf: pz, float ofs b*128 + e
    __shared__ float4 smem4[9728];
    __shared__ int sids[NB], eids[NB];

    float* TABf = (float*)smem4;
    float* EAf  = TABf + 32768;
    float* PZf  = EAf + 4096;
    char* KNs_base = (char*)smem4;
    char* W1s_base = KNs_base + 32768;
    char* W2s_base = KNs_base + 65536;

    const int tid  = threadIdx.x;
    const int b0   = blockIdx.x * NB;
    const int lane = tid & 63, wid = tid >> 6;
    const int l31 = lane & 31, g32 = lane >> 5;
    const int l15 = lane & 15, g16 = lane >> 4;

    if (tid < NB) {
        int b = b0 + tid;
        sids[tid] = stu_id[b < B ? b : 0];
        eids[tid] = exer_id[b < B ? b : 0];
    }
    // ---- stage kn, |W1b|, |W2b| as bf16, row 256B, chunk-XOR-swizzled ----
    for (int i = tid; i < 128 * 16; i += 512) {
        int row = i >> 4, c = i & 15;
        int byt = row * 256 + (((c << 4)) ^ ((row & 7) << 4));
        const float4* sk = (const float4*)(kn + (size_t)row * D + c * 8);
        *(s16x8*)(KNs_base + byt) = pack8(sk[0], sk[1]);
        const float4* s1 = (const float4*)(W1 + (size_t)row * (2 * D) + D + c * 8);
        *(s16x8*)(W1s_base + byt) = pack8abs(s1[0], s1[1]);
        const float4* s2 = (const float4*)(W2 + (size_t)row * (2 * D) + D + c * 8);
        *(s16x8*)(W2s_base + byt) = pack8abs(s2[0], s2[1]);
    }
    __syncthreads();

    // ---- issue scattered gather loads EARLY (hide under tables GEMM) ----
    const int sid_l = sids[l15], eid_l = eids[l15];
    const int erow  = wid * 16 + l15;
    float4 ga[8], ge[8];
    #pragma unroll
    for (int q = 0; q < 4; ++q) {
        int d = q * 32 + g16 * 8;
        const float4* pa = (const float4*)(stu_v + (size_t)sid_l * D + d);
        ga[2*q] = pa[0]; ga[2*q+1] = pa[1];
        const float4* pe = (const float4*)(exer_v + (size_t)eid_l * D + d);
        ge[2*q] = pe[0]; ge[2*q+1] = pe[1];
    }

    // ---- tables GEMM: wave = (et = wid&3, W = wid<4), A-frag hoisted ----
    f32x16 t0acc = {0}, t1acc = {0}, t2acc = {0}, t3acc = {0};
    {
        const char* Wsb = (wid < 4) ? W1s_base : W2s_base;
        const int er = (wid & 3) * 32 + l31;
        const int eswz = (er & 7) << 4;
        const int kswz = (l31 & 7) << 4;
        #pragma unroll
        for (int q = 0; q < 8; ++q) {
            int dby = q * 32 + g32 * 16;
            s16x8 a_  = *(const s16x8*)(Wsb + er * 256 + (dby ^ eswz));
            s16x8 bb0 = *(const s16x8*)(KNs_base + (  0 + l31) * 256 + (dby ^ kswz));
            s16x8 bb1 = *(const s16x8*)(KNs_base + ( 32 + l31) * 256 + (dby ^ kswz));
            s16x8 bb2 = *(const s16x8*)(KNs_base + ( 64 + l31) * 256 + (dby ^ kswz));
            s16x8 bb3 = *(const s16x8*)(KNs_base + ( 96 + l31) * 256 + (dby ^ kswz));
            t0acc = __builtin_amdgcn_mfma_f32_32x32x16_bf16(a_, bb0, t0acc, 0, 0, 0);
            t1acc = __builtin_amdgcn_mfma_f32_32x32x16_bf16(a_, bb1, t1acc, 0, 0, 0);
            t2acc = __builtin_amdgcn_mfma_f32_32x32x16_bf16(a_, bb2, t2acc, 0, 0, 0);
            t3acc = __builtin_amdgcn_mfma_f32_32x32x16_bf16(a_, bb3, t3acc, 0, 0, 0);
        }
    }

    // ---- prep GEMM: C[16b x 16e] per wave, A from regs, B rows from global ----
    f32x4 accS = {0, 0, 0, 0}, accE = {0, 0, 0, 0};
    #pragma unroll
    for (int q = 0; q < 4; ++q) {
        int d = q * 32 + g16 * 8;
        const float4* pb = (const float4*)(W1 + (size_t)erow * (2 * D) + d);
        accS = __builtin_amdgcn_mfma_f32_16x16x32_bf16(
            pack8(ga[2*q], ga[2*q+1]), pack8abs(pb[0], pb[1]), accS, 0, 0, 0);
        const float4* pc = (const float4*)(W2 + (size_t)erow * (2 * D) + d);
        accE = __builtin_amdgcn_mfma_f32_16x16x32_bf16(
            pack8(ge[2*q], ge[2*q+1]), pack8abs(pc[0], pc[1]), accE, 0, 0, 0);
    }
    // EA writes (region disjoint from staging -> no sync needed yet)
    #pragma unroll
    for (int r = 0; r < 4; ++r) {
        int b = g16 * 4 + r;
        int eo = b * 256 + 2 * erow;
        EAf[eo]     = negexp(accS[r]);
        EAf[eo + 1] = negexp(accE[r]);
    }
    // ---- PZ: disc * |w3|, thread = (b = tid>>5, 4 e's) ----
    {
        int b = tid >> 5, e4 = (tid & 31) << 2;
        float4 sq = *(const float4*)(stu_q + (size_t)sids[b] * D + e4);
        float4 ek = *(const float4*)(exer_k + (size_t)eids[b] * D + e4);
        float4 w3 = *(const float4*)(W3 + e4);
        float4 z;
        z.x = sigf(sq.x * ek.x) * fabsf(w3.x);
        z.y = sigf(sq.y * ek.y) * fabsf(w3.y);
        z.z = sigf(sq.z * ek.z) * fabsf(w3.z);
        z.w = sigf(sq.w * ek.w) * fabsf(w3.w);
        *(float4*)(PZf + b * D + e4) = z;
    }
    __syncthreads();   // all staged-LDS reads done -> TAB may overwrite

    TWRITE(0, t0acc) TWRITE(1, t1acc) TWRITE(2, t2acc) TWRITE(3, t3acc)
    __syncthreads();   // TAB/EA/PZ ready

    // ---------------- Phase B: e-sliced waves ----------------
    // wave wid owns e in [16*wid, 16*wid+16); lane owns k = 2*lane, 2*lane+1;
    // acc[r] = partial sum over this wave's e-slice for row r.
    const float4* TAB4 = (const float4*)TABf;
    const float4* EA4  = (const float4*)EAf;
    const float2* PZ2  = (const float2*)PZf;

    float2 acc[16];
    #pragma unroll
    for (int r = 0; r < 16; ++r) acc[r] = make_float2(0.f, 0.f);

    for (int jj = 0; jj < 8; ++jj) {
        const int e0 = wid * 16 + 2 * jj;
        const int jg = wid * 8 + jj;
        float4 t0 = TAB4[e0 * 64 + lane];          // per-lane b128, read ONCE/block
        float4 t1 = TAB4[(e0 + 1) * 64 + lane];
        #pragma unroll
        for (int r = 0; r < 16; ++r) {
            float4 eA = EA4[r * 64 + jg];          // wave-uniform broadcast
            float2 zA = PZ2[r * 64 + jg];
            CORE(eA.x, eA.y, t0, zA.x, acc[r].x, acc[r].y);
            CORE(eA.z, eA.w, t1, zA.y, acc[r].x, acc[r].y);
        }
    }
    __syncthreads();                     // all TAB reads done -> RED may alias

    float2* RED = (float2*)TABf;         // [wave][row][lane] partials (16 KB... 8*16*64*8B=64KB)
    #pragma unroll
    for (int r = 0; r < 16; ++r)
        RED[(wid * 16 + r) * 64 + lane] = acc[r];
    __syncthreads();

    // ---- cross-wave reduce + epilogue: rows rA=2*wid, rB=2*wid+1 ----
    const float b3v = b3[0];
    const int rA = 2 * wid, rB = 2 * wid + 1;
    const int bA = b0 + rA, bB = b0 + rB;

    float2 sA = make_float2(0.f, 0.f), sB = make_float2(0.f, 0.f);
    #pragma unroll
    for (int w = 0; w < 8; ++w) {
        float2 pA = RED[(w * 16 + rA) * 64 + lane];
        float2 pB = RED[(w * 16 + rB) * 64 + lane];
        sA.x += pA.x; sA.y += pA.y;
        sB.x += pB.x; sB.y += pB.y;
    }

    float o0a = sigf(sA.x + b3v), o1a = sigf(sA.y + b3v);
    float o0b = sigf(sB.x + b3v), o1b = sigf(sB.y + b3v);
    float na = 0.f, da = 0.f, nb = 0.f, db = 0.f;
    if (bA < B) {
        float2 kqa = *(const float2*)(kq + (size_t)bA * D + 2 * lane);
        na = fmaf(o0a, kqa.x, o1a * kqa.y); da = kqa.x + kqa.y;
    }
    if (bB < B) {
        float2 kqb = *(const float2*)(kq + (size_t)bB * D + 2 * lane);
        nb = fmaf(o0b, kqb.x, o1b * kqb.y); db = kqb.x + kqb.y;
    }
    #pragma unroll
    for (int off = 32; off > 0; off >>= 1) {
        na += __shfl_xor(na, off); da += __shfl_xor(da, off);
        nb += __shfl_xor(nb, off); db += __shfl_xor(db, off);
    }
    if (lane == 0) {
        if (bA < B) out[bA] = na / da;
        if (bB < B) out[bB] = nb / db;
    }
}

// ---------------------------------------------------------------------------
extern "C" void kernel_launch(void* const* d_in, const int* in_sizes, int n_in,
                              void* d_out, int out_size, void* d_ws, size_t ws_size,
                              hipStream_t stream)
{
    const int*   stu_id      = (const int*)  d_in[0];
    const int*   exer_id     = (const int*)  d_in[1];
    const float* kq          = (const float*)d_in[2];
    const float* student_q   = (const float*)d_in[3];
    const float* exercise_k  = (const float*)d_in[4];
    const float* student_v   = (const float*)d_in[5];
    const float* exercise_v  = (const float*)d_in[6];
    const float* knowledge_v = (const float*)d_in[7];
    const float* W1 = (const float*)d_in[8];
    const float* b1 = (const float*)d_in[9];
    const float* W2 = (const float*)d_in[10];
    const float* b2 = (const float*)d_in[11];
    const float* W3 = (const float*)d_in[12];
    const float* b3 = (const float*)d_in[13];
    float* out = (float*)d_out;
    const int B = in_sizes[0];

    int nblk = (B + NB - 1) / NB;
    fused_kernel<<<nblk, 512, 0, stream>>>(
        stu_id, exer_id, kq, student_q, exercise_k, student_v, exercise_v,
        knowledge_v, W1, b1, W2, b2, W3, b3, out, B);
}